// Round 11
// baseline (1355.172 us; speedup 1.0000x reference)
//
#include <hip/hip_runtime.h>

// Problem constants
#define N_ANCH   589824     // 256*256*9
#define TOPK     12000
#define KPAD     12032      // 188*64
#define NW       188        // mask words per row
#define OUTN     2000
#define CAP      32768      // candidate buffer capacity
#define GRID     1024       // cooperative grid: 4 blocks/CU (empirically launchable, R7)

typedef unsigned long long u64;

// 9 base anchors (ratio-major, scale-minor), widths/heights (x1-x0+1)
__constant__ float c_aw[9] = {184.f, 368.f, 736.f, 128.f, 256.f, 512.f,  88.f, 176.f, 352.f};
__constant__ float c_ah[9] = { 96.f, 192.f, 384.f, 128.f, 256.f, 512.f, 176.f, 352.f, 704.f};

__device__ __forceinline__ void decode_one(int i, const float4* __restrict__ delta,
                                           float4* box, bool* valid) {
#pragma clang fp contract(off)
    int a    = i % 9;
    int cell = i / 9;
    int gx = cell & 255;
    int gy = cell >> 8;
    float w = c_aw[a], h = c_ah[a];
    float cx = (float)gx * 16.0f + 8.0f;
    float cy = (float)gy * 16.0f + 8.0f;
    float4 d = delta[i];
    float pcx = d.x * w + cx;
    float pcy = d.y * h + cy;
    float pw  = expf(d.z) * w;
    float ph  = expf(d.w) * h;
    float x0 = fminf(fmaxf(pcx - 0.5f * pw, 0.f), 4096.f);
    float y0 = fminf(fmaxf(pcy - 0.5f * ph, 0.f), 4096.f);
    float x1 = fminf(fmaxf(pcx + 0.5f * pw, 0.f), 4096.f);
    float y1 = fminf(fmaxf(pcy + 0.5f * ph, 0.f), 4096.f);
    *box = make_float4(x0, y0, x1, y1);
    *valid = (x1 - x0 >= 16.f) && (y1 - y0 >= 16.f);
}

// Lightweight agent-scope grid barrier. Slot counters zeroed by host memset.
__device__ __forceinline__ void gbar(unsigned* bar, int slot, bool wait) {
    __syncthreads();                     // drains this block's vmem
    if (threadIdx.x == 0) {
        __threadfence();                 // release
        atomicAdd(&bar[slot * 32], 1u);
        if (wait) {
            while (__hip_atomic_load(&bar[slot * 32], __ATOMIC_RELAXED,
                                     __HIP_MEMORY_SCOPE_AGENT) < gridDim.x)
                __builtin_amdgcn_s_sleep(8);
            __threadfence();             // acquire
        }
    }
    __syncthreads();
}

__global__ __launch_bounds__(256, 4) void k_fused(
        const float4* __restrict__ delta, const float2* __restrict__ score,
        unsigned* __restrict__ ukey, unsigned* __restrict__ hist1,
        unsigned* __restrict__ hist2, unsigned* __restrict__ ctrl,
        unsigned* __restrict__ bar, u64* __restrict__ cand,
        float4* __restrict__ sbox, u64* __restrict__ mask,
        float4* __restrict__ out) {
    int tid = threadIdx.x;
    int bid = blockIdx.x;
    int lane = tid & 63;
    int wave = tid >> 6;

    __shared__ unsigned lh[256];
    __shared__ unsigned ss[256];
    __shared__ u64 tile[256];
    __shared__ float4 cbox[256];
    __shared__ unsigned s_u[4];
    __shared__ u64 s_rw[2];

    // ---------- P1: decode + key + LDS-aggregated level-1 histogram (bits 31:24) ----------
    lh[tid] = 0u;
    __syncthreads();
    for (int i = bid * 256 + tid; i < N_ANCH; i += GRID * 256) {
        float4 box; bool valid;
        decode_one(i, delta, &box, &valid);
        unsigned u = 0u;
        if (valid) {
            unsigned b = __float_as_uint(score[i].y);
            u = (b & 0x80000000u) ? ~b : (b | 0x80000000u);  // order-preserving; 0 = dead
        }
        ukey[i] = u;
        atomicAdd(&lh[u >> 24], 1u);
    }
    __syncthreads();
    if (lh[tid]) atomicAdd(&hist1[tid], lh[tid]);
    gbar(bar, 0, true);

    // ---------- P2: b1 (per-block redundant scan) + level-2 histogram ----------
    ss[tid] = hist1[tid];
    lh[tid] = 0u;
    if (tid == 0) s_u[0] = 0u;
    __syncthreads();
    for (int d = 1; d < 256; d <<= 1) {
        unsigned v = (tid + d < 256) ? ss[tid + d] : 0u;
        __syncthreads();
        ss[tid] += v;
        __syncthreads();
    }
    if (ss[tid] >= (unsigned)TOPK && (tid == 255 || ss[tid + 1] < (unsigned)TOPK))
        s_u[0] = (unsigned)tid;
    __syncthreads();
    unsigned b1 = s_u[0];
    for (int i = bid * 256 + tid; i < N_ANCH; i += GRID * 256) {
        unsigned u = ukey[i];
        if ((u >> 24) == b1) atomicAdd(&lh[(u >> 16) & 255u], 1u);
    }
    __syncthreads();
    if (lh[tid]) atomicAdd(&hist2[tid], lh[tid]);
    gbar(bar, 1, true);

    // ---------- P3: P (two redundant scans) + compact ----------
    ss[tid] = hist1[tid];
    if (tid == 0) { s_u[0] = 0u; s_u[1] = 0u; }
    __syncthreads();
    for (int d = 1; d < 256; d <<= 1) {
        unsigned v = (tid + d < 256) ? ss[tid + d] : 0u;
        __syncthreads();
        ss[tid] += v;
        __syncthreads();
    }
    if (ss[tid] >= (unsigned)TOPK && (tid == 255 || ss[tid + 1] < (unsigned)TOPK)) {
        s_u[0] = (unsigned)tid;
        s_u[1] = (tid == 255) ? 0u : ss[tid + 1];
    }
    __syncthreads();
    b1 = s_u[0];
    unsigned ab1 = s_u[1];
    ss[tid] = hist2[tid];
    if (tid == 0) s_u[2] = (b1 << 8);            // fallback b2 = 0 (take-all)
    __syncthreads();
    for (int d = 1; d < 256; d <<= 1) {
        unsigned v = (tid + d < 256) ? ss[tid + d] : 0u;
        __syncthreads();
        ss[tid] += v;
        __syncthreads();
    }
    unsigned target = (unsigned)TOPK - ab1;
    if (ss[tid] >= target && (tid == 255 || ss[tid + 1] < target))
        s_u[2] = (b1 << 8) | (unsigned)tid;
    __syncthreads();
    unsigned P = s_u[2];
    for (int i = bid * 256 + tid; i < N_ANCH; i += GRID * 256) {
        unsigned u = ukey[i];
        bool pred = (u != 0u) && ((u >> 16) >= P);
        u64 m = __ballot(pred);
        if (m) {
            int leader = __ffsll(m) - 1;
            unsigned base = 0;
            if (lane == leader) base = atomicAdd(&ctrl[3], (unsigned)__popcll(m));
            base = __shfl(base, leader);
            if (pred) {
                u64 below = m & ((1ull << lane) - 1ull);
                unsigned pos = base + (unsigned)__popcll(below);
                if (pos < CAP) cand[pos] = ((u64)u << 32) | (unsigned)(~i);
            }
        }
    }
    gbar(bar, 2, true);

    // ---------- P4: exact rank + decode into sbox; zero-fill pad ranks ----------
    unsigned cnt = ctrl[3];
    int C = (int)(cnt < (unsigned)CAP ? cnt : (unsigned)CAP);
    if (bid * 256 < C) {                           // block-uniform participation
        int t = bid * 256 + tid;
        u64 mykey = (t < C) ? cand[t] : ~0ull;
        int rank = 0;
        for (int j0 = 0; j0 < C; j0 += 256) {
            int j = j0 + tid;
            tile[tid] = (j < C) ? cand[j] : 0ull;
            __syncthreads();
            int lim = (C - j0 < 256) ? (C - j0) : 256;
            #pragma unroll 4
            for (int jj = 0; jj < lim; ++jj) rank += (tile[jj] > mykey) ? 1 : 0;
            __syncthreads();
        }
        if (t < C && rank < TOPK) {
            int idx = (int)(~(unsigned)mykey);
            float4 box; bool v;
            decode_one(idx, delta, &box, &v);
            sbox[rank] = box;
        }
    }
    int nv = C < TOPK ? C : TOPK;
    {
        int r = bid * 256 + tid;                   // GRID*256 >= KPAD
        if (r >= nv && r < KPAD) sbox[r] = make_float4(0.f, 0.f, 0.f, 0.f);
    }
    gbar(bar, 3, true);

    // ---------- P5: suppression bitmask, ROW-major mask[r*NW+cb], upper tri ----------
    for (int tix = bid; tix < 188 * 47; tix += GRID) {
        int rb = tix / 47;
        int cb0 = (tix % 47) * 4;
        if (cb0 + 3 < rb) continue;                // block-uniform skip
        __syncthreads();
        cbox[tid] = sbox[cb0 * 64 + tid];
        __syncthreads();
        int cb = cb0 + wave;
        if (cb >= rb) {
            int r = rb * 64 + lane;
            float4 me = sbox[r];
            float areaMe = (me.z - me.x) * (me.w - me.y);
            u64 bits = 0ull;
            for (int j = 0; j < 64; ++j) {
                float4 o = cbox[wave * 64 + j];
                float xx0 = fmaxf(me.x, o.x);
                float yy0 = fmaxf(me.y, o.y);
                float xx1 = fminf(me.z, o.z);
                float yy1 = fminf(me.w, o.w);
                float iw = fmaxf(xx1 - xx0, 0.f);
                float ih = fmaxf(yy1 - yy0, 0.f);
                float inter = iw * ih;
                float areaO = (o.z - o.x) * (o.w - o.y);
                float denom = fmaxf(areaMe + areaO - inter, 1e-8f);
                float iou = inter / denom;
                if (iou > 0.7f && (cb * 64 + j) != r) bits |= (1ull << j);
            }
            mask[(size_t)r * NW + cb] = bits;
        }
    }
    gbar(bar, 4, bid == 0);                        // only block 0 waits
    if (bid != 0) return;

    // ---------- P6: blocked greedy reduce (block 0), deferred 16-deep fold ----------
    int nblocks = (nv + 63) >> 6;
    u64 removed_t = ~0ull;                         // thread t owns column word t
    if (tid < NW) {
        long long lo = (long long)tid * 64;
        if (lo + 64 <= (long long)nv) removed_t = 0ull;
        else if (lo < (long long)nv)
            removed_t = ~((1ull << (unsigned)(nv - lo)) - 1ull);
    }

    int nk = 0;
    u64 p0=0,p1=0,p2=0,p3=0,p4=0,p5=0,p6=0,p7=0;
    u64 p8=0,p9=0,p10=0,p11=0,p12=0,p13=0,p14=0,p15=0;
    u64 dgnext = 0ull;
    if (nblocks > 0) dgnext = mask[(size_t)lane * NW + 0];  // diag of block 0

    for (int b = 0; b < nblocks; ++b) {
        // fold pending OR loads (issued last iteration; coalesced strips)
        removed_t |= ((p0|p1)|(p2|p3)) | ((p4|p5)|(p6|p7));
        removed_t |= ((p8|p9)|(p10|p11)) | ((p12|p13)|(p14|p15));
        p0=p1=p2=p3=p4=p5=p6=p7=0ull;
        p8=p9=p10=p11=p12=p13=p14=p15=0ull;
        u64 dg = dgnext;
        if (tid == b) s_rw[b & 1] = removed_t;     // word b now final
        __syncthreads();
        u64 rw = s_rw[b & 1];
        if (b + 1 < nblocks)                       // prefetch next diag
            dgnext = mask[(size_t)((b + 1) * 64 + lane) * NW + (b + 1)];

        // resolve via IoU symmetry: lane tests bits of ITS OWN diag word
        bool alive = ((rw >> lane) & 1ull) == 0ull;
        int budget = OUTN - nk;
        u64 keptmask = 0ull;
        int kc = 0;
        while (kc < budget) {
            u64 m = __ballot(alive);
            if (!m) break;
            int j = __ffsll(m) - 1;                // uniform
            keptmask |= (1ull << j);
            ++kc;
            alive = alive && (lane != j) && (((dg >> j) & 1ull) == 0ull);
        }

        if (wave == 0 && ((keptmask >> lane) & 1ull)) {
            int pos = nk + (int)__popcll(keptmask & ((1ull << lane) - 1ull));
            out[pos] = sbox[b * 64 + lane];
        }
        nk += kc;
        if (nk >= OUTN) break;

        // issue OR loads for next-iteration fold: mask[row*NW + tid] is
        // CONTIGUOUS across threads (coalesced strip per kept row)
        if (kc > 0 && tid > b && tid < NW) {
            const u64* mt = mask + tid;
            u64 km = keptmask;
            int jf = __ffsll(km) - 1;
            int i0 = jf;                          km &= km - 1;
            int i1  = km ? __ffsll(km) - 1 : jf;  km &= km - 1;
            int i2  = km ? __ffsll(km) - 1 : jf;  km &= km - 1;
            int i3  = km ? __ffsll(km) - 1 : jf;  km &= km - 1;
            int i4  = km ? __ffsll(km) - 1 : jf;  km &= km - 1;
            int i5  = km ? __ffsll(km) - 1 : jf;  km &= km - 1;
            int i6  = km ? __ffsll(km) - 1 : jf;  km &= km - 1;
            int i7  = km ? __ffsll(km) - 1 : jf;  km &= km - 1;
            int i8  = km ? __ffsll(km) - 1 : jf;  km &= km - 1;
            int i9  = km ? __ffsll(km) - 1 : jf;  km &= km - 1;
            int i10 = km ? __ffsll(km) - 1 : jf;  km &= km - 1;
            int i11 = km ? __ffsll(km) - 1 : jf;  km &= km - 1;
            int i12 = km ? __ffsll(km) - 1 : jf;  km &= km - 1;
            int i13 = km ? __ffsll(km) - 1 : jf;  km &= km - 1;
            int i14 = km ? __ffsll(km) - 1 : jf;  km &= km - 1;
            int i15 = km ? __ffsll(km) - 1 : jf;  km &= km - 1;
            size_t rb8 = (size_t)b * 64 * NW;
            p0  = mt[rb8 + (size_t)i0  * NW];
            p1  = mt[rb8 + (size_t)i1  * NW];
            p2  = mt[rb8 + (size_t)i2  * NW];
            p3  = mt[rb8 + (size_t)i3  * NW];
            p4  = mt[rb8 + (size_t)i4  * NW];
            p5  = mt[rb8 + (size_t)i5  * NW];
            p6  = mt[rb8 + (size_t)i6  * NW];
            p7  = mt[rb8 + (size_t)i7  * NW];
            p8  = mt[rb8 + (size_t)i8  * NW];
            p9  = mt[rb8 + (size_t)i9  * NW];
            p10 = mt[rb8 + (size_t)i10 * NW];
            p11 = mt[rb8 + (size_t)i11 * NW];
            p12 = mt[rb8 + (size_t)i12 * NW];
            p13 = mt[rb8 + (size_t)i13 * NW];
            p14 = mt[rb8 + (size_t)i14 * NW];
            p15 = mt[rb8 + (size_t)i15 * NW];
            while (km) {                           // rare: kc > 16
                int j = __ffsll(km) - 1; km &= km - 1;
                removed_t |= mt[rb8 + (size_t)j * NW];
            }
        }
    }

    float4 z = make_float4(0.f, 0.f, 0.f, 0.f);
    for (int p = nk + tid; p < OUTN; p += 256) out[p] = z;
}

extern "C" void kernel_launch(void* const* d_in, const int* in_sizes, int n_in,
                              void* d_out, int out_size, void* d_ws, size_t ws_size,
                              hipStream_t stream) {
    const float4* delta = (const float4*)d_in[0];
    const float2* score = (const float2*)d_in[1];
    char* ws = (char*)d_ws;

    // Workspace layout (bytes)
    unsigned* ukey  = (unsigned*)(ws + 0);         // N_ANCH u32
    u64*      cand  = (u64*)(ws + 2359296);        // CAP u64
    unsigned* hist1 = (unsigned*)(ws + 2621440);   // 256 u32  -- memset region start
    unsigned* hist2 = (unsigned*)(ws + 2622464);   // 256 u32
    unsigned* ctrl  = (unsigned*)(ws + 2623488);   // 16 u32
    unsigned* bar   = (unsigned*)(ws + 2623552);   // 5 slots x 128B = 640B
    float4*   sbox  = (float4*)(ws + 2624192);     // KPAD float4 (pad zeroed in-kernel)
    u64*      mask  = (u64*)(ws + 2816704);        // KPAD*NW u64, ROW-major
    float4*   outp  = (float4*)d_out;

    hipMemsetAsync(ws + 2621440, 0, 2752, stream); // hist1+hist2+ctrl+bar

    void* args[] = {&delta, &score, &ukey, &hist1, &hist2, &ctrl, &bar,
                    &cand, &sbox, &mask, &outp};
    hipLaunchCooperativeKernel((const void*)k_fused, dim3(GRID), dim3(256),
                               args, 0, stream);
}

// Round 12
// 1184.257 us; speedup vs baseline: 1.1443x; 1.1443x over previous
//
#include <hip/hip_runtime.h>

// Problem constants
#define N_ANCH   589824     // 256*256*9
#define TOPK     12000
#define KPAD     12032      // 188*64
#define NW       188        // mask words per row
#define OUTN     2000
#define CAP      32768      // candidate buffer capacity
#define NBIN     8192       // histogram bins (bits 31:19 of ordered key)

typedef unsigned long long u64;

// 9 base anchors (ratio-major, scale-minor), widths/heights (x1-x0+1)
__constant__ float c_aw[9] = {184.f, 368.f, 736.f, 128.f, 256.f, 512.f,  88.f, 176.f, 352.f};
__constant__ float c_ah[9] = { 96.f, 192.f, 384.f, 128.f, 256.f, 512.f, 176.f, 352.f, 704.f};

__device__ __forceinline__ void decode_one(int i, const float4* __restrict__ delta,
                                           float4* box, bool* valid) {
#pragma clang fp contract(off)
    int a    = i % 9;
    int cell = i / 9;
    int gx = cell & 255;
    int gy = cell >> 8;
    float w = c_aw[a], h = c_ah[a];
    float cx = (float)gx * 16.0f + 8.0f;
    float cy = (float)gy * 16.0f + 8.0f;
    float4 d = delta[i];
    float pcx = d.x * w + cx;
    float pcy = d.y * h + cy;
    float pw  = expf(d.z) * w;
    float ph  = expf(d.w) * h;
    float x0 = fminf(fmaxf(pcx - 0.5f * pw, 0.f), 4096.f);
    float y0 = fminf(fmaxf(pcy - 0.5f * ph, 0.f), 4096.f);
    float x1 = fminf(fmaxf(pcx + 0.5f * pw, 0.f), 4096.f);
    float y1 = fminf(fmaxf(pcy + 0.5f * ph, 0.f), 4096.f);
    *box = make_float4(x0, y0, x1, y1);
    *valid = (x1 - x0 >= 16.f) && (y1 - y0 >= 16.f);
}

// Decode + key + single 8192-bin LDS histogram (bits 31:19).
__global__ __launch_bounds__(256) void k_score(const float4* __restrict__ delta,
                                               const float2* __restrict__ score,
                                               unsigned* __restrict__ ukey,
                                               unsigned* __restrict__ hist) {
    __shared__ unsigned lh[NBIN];
    int tid = threadIdx.x;
    for (int k = tid; k < NBIN; k += 256) lh[k] = 0u;
    __syncthreads();
    for (int i = blockIdx.x * 256 + tid; i < N_ANCH; i += gridDim.x * 256) {
        float4 box; bool valid;
        decode_one(i, delta, &box, &valid);
        unsigned u = 0u;
        if (valid) {
            unsigned b = __float_as_uint(score[i].y);
            u = (b & 0x80000000u) ? ~b : (b | 0x80000000u);  // order-preserving; 0 = dead
        }
        ukey[i] = u;
        atomicAdd(&lh[u >> 19], 1u);
    }
    __syncthreads();
    for (int k = tid; k < NBIN; k += 256) {
        unsigned c = lh[k];
        if (c) atomicAdd(&hist[k], c);
    }
}

// Per-block redundant threshold scan (bin-exact) + compact.
__global__ __launch_bounds__(256) void k_compact(const unsigned* __restrict__ ukey,
                                                 const unsigned* __restrict__ hist,
                                                 unsigned* __restrict__ cnt,
                                                 u64* __restrict__ cand) {
    __shared__ unsigned ss[256];
    __shared__ unsigned s_B;
    int tid = threadIdx.x;
    int lane = tid & 63;
    const uint4* hb = (const uint4*)hist + tid * 8;    // 32 bins/thread
    unsigned cs = 0;
    #pragma unroll
    for (int k = 0; k < 8; ++k) {
        uint4 h = hb[k];
        cs += h.x + h.y + h.z + h.w;
    }
    ss[tid] = cs;
    if (tid == 0) s_B = 0u;
    __syncthreads();
    for (int d = 1; d < 256; d <<= 1) {                // suffix scan over chunk sums
        unsigned v = (tid + d < 256) ? ss[tid + d] : 0u;
        __syncthreads();
        ss[tid] += v;
        __syncthreads();
    }
    if (ss[tid] >= (unsigned)TOPK && (tid == 255 || ss[tid + 1] < (unsigned)TOPK)) {
        unsigned acc = (tid == 255) ? 0u : ss[tid + 1];
        unsigned B = (unsigned)(tid * 32);
        for (int j = 31; j >= 0; --j) {
            acc += hist[tid * 32 + j];
            if (acc >= (unsigned)TOPK) { B = (unsigned)(tid * 32 + j); break; }
        }
        s_B = B;
    }
    __syncthreads();
    unsigned B = s_B;
    for (int i = blockIdx.x * 256 + tid; i < N_ANCH; i += gridDim.x * 256) {
        unsigned u = ukey[i];
        bool pred = (u != 0u) && ((u >> 19) >= B);
        u64 m = __ballot(pred);
        if (m) {
            int leader = __ffsll(m) - 1;
            unsigned base = 0;
            if (lane == leader) base = atomicAdd(cnt, (unsigned)__popcll(m));
            base = __shfl(base, leader);
            if (pred) {
                u64 below = m & ((1ull << lane) - 1ull);
                unsigned pos = base + (unsigned)__popcll(below);
                if (pos < CAP) cand[pos] = ((u64)u << 32) | (unsigned)(~i);
            }
        }
    }
}

// Exact rank + decode into sbox; zero-fills pad ranks [nv, KPAD) (disjoint, race-free).
__global__ __launch_bounds__(256) void k_rankdec(const u64* __restrict__ cand,
                                                 const unsigned* __restrict__ ctrl,
                                                 const float4* __restrict__ delta,
                                                 float4* __restrict__ sboxes) {
    unsigned cnt = ctrl[3];
    int C = (int)(cnt < (unsigned)CAP ? cnt : (unsigned)CAP);
    int nv = C < TOPK ? C : TOPK;
    int t = blockIdx.x * 256 + threadIdx.x;
    if (t >= nv && t < KPAD) sboxes[t] = make_float4(0.f, 0.f, 0.f, 0.f);
    if ((int)(blockIdx.x * 256) >= C) return;
    u64 mykey = (t < C) ? cand[t] : ~0ull;
    int rank = 0;
    __shared__ u64 tile[256];
    for (int j0 = 0; j0 < C; j0 += 256) {
        int j = j0 + threadIdx.x;
        tile[threadIdx.x] = (j < C) ? cand[j] : 0ull;
        __syncthreads();
        int lim = (C - j0 < 256) ? (C - j0) : 256;
        #pragma unroll 4
        for (int jj = 0; jj < lim; ++jj) rank += (tile[jj] > mykey) ? 1 : 0;
        __syncthreads();
    }
    if (t < C && rank < TOPK) {
        int idx = (int)(~(unsigned)mykey);
        float4 box; bool v;
        decode_one(idx, delta, &box, &v);
        sboxes[rank] = box;
    }
}

// Suppression bitmask, ROW-major mask[r*NW+cb], upper triangle. Also writes the
// compact diag/superdiag array dgsd[r] = {mask[r][rb], mask[r][rb+1]} for the
// reduce's coalesced prefetch.
__global__ __launch_bounds__(64) void k_mask(const float4* __restrict__ sboxes,
                                             u64* __restrict__ mask,
                                             u64* __restrict__ dgsd) {
    int rb = blockIdx.y;
    int cb0 = blockIdx.x * 4;
    if (cb0 + 3 < rb) return;
    int tid = threadIdx.x;
    int r = rb * 64 + tid;
    float4 me = sboxes[r];
    float areaMe = (me.z - me.x) * (me.w - me.y);
    __shared__ float4 cbox[64];
    for (int q = 0; q < 4; ++q) {                 // wave-uniform guard: 1-wave block
        int cb = cb0 + q;
        if (cb < rb) continue;
        __syncthreads();
        cbox[tid] = sboxes[cb * 64 + tid];
        __syncthreads();
        u64 bits = 0ull;
        for (int j = 0; j < 64; ++j) {
            float4 o = cbox[j];
            float xx0 = fmaxf(me.x, o.x);
            float yy0 = fmaxf(me.y, o.y);
            float xx1 = fminf(me.z, o.z);
            float yy1 = fminf(me.w, o.w);
            float iw = fmaxf(xx1 - xx0, 0.f);
            float ih = fmaxf(yy1 - yy0, 0.f);
            float inter = iw * ih;
            float areaO = (o.z - o.x) * (o.w - o.y);
            float denom = fmaxf(areaMe + areaO - inter, 1e-8f);
            float iou = inter / denom;
            if (iou > 0.7f && (cb * 64 + j) != r) bits |= (1ull << j);
        }
        mask[(size_t)r * NW + cb] = bits;
        if (cb == rb)     dgsd[2 * r]     = bits;   // diagonal word
        if (cb == rb + 1) dgsd[2 * r + 1] = bits;   // superdiagonal word
    }
}

// Blocked greedy reduce with LAG-2 deferred fold:
// - word b publish = removed_t (folds through block b-2) | s_sup (block b-1's
//   superdiag contribution, computed in-register last iteration).
// - strip loads for block b's kept rows are issued at iter b, folded at iter b+2
//   (two pending register sets, parity-indexed) -> full-iteration latency window.
// - diag+superdiag prefetch = one coalesced 16B/lane load from dgsd.
#define EXTRACT16()                                            \
    u64 km = keptmask;                                         \
    int jf = __ffsll(km) - 1;                                  \
    int i0 = jf;                          km &= km - 1;        \
    int i1  = km ? __ffsll(km) - 1 : jf;  km &= km - 1;        \
    int i2  = km ? __ffsll(km) - 1 : jf;  km &= km - 1;        \
    int i3  = km ? __ffsll(km) - 1 : jf;  km &= km - 1;        \
    int i4  = km ? __ffsll(km) - 1 : jf;  km &= km - 1;        \
    int i5  = km ? __ffsll(km) - 1 : jf;  km &= km - 1;        \
    int i6  = km ? __ffsll(km) - 1 : jf;  km &= km - 1;        \
    int i7  = km ? __ffsll(km) - 1 : jf;  km &= km - 1;        \
    int i8  = km ? __ffsll(km) - 1 : jf;  km &= km - 1;        \
    int i9  = km ? __ffsll(km) - 1 : jf;  km &= km - 1;        \
    int i10 = km ? __ffsll(km) - 1 : jf;  km &= km - 1;        \
    int i11 = km ? __ffsll(km) - 1 : jf;  km &= km - 1;        \
    int i12 = km ? __ffsll(km) - 1 : jf;  km &= km - 1;        \
    int i13 = km ? __ffsll(km) - 1 : jf;  km &= km - 1;        \
    int i14 = km ? __ffsll(km) - 1 : jf;  km &= km - 1;        \
    int i15 = km ? __ffsll(km) - 1 : jf;  km &= km - 1;

#define ISSUE(P)                                               \
    if (kc > 0 && tid > b + 1 && tid < NW) {                   \
        const u64* mt2 = mask + (size_t)b * 64 * NW + tid;     \
        P##0  = mt2[(size_t)i0  * NW];                         \
        P##1  = mt2[(size_t)i1  * NW];                         \
        P##2  = mt2[(size_t)i2  * NW];                         \
        P##3  = mt2[(size_t)i3  * NW];                         \
        P##4  = mt2[(size_t)i4  * NW];                         \
        P##5  = mt2[(size_t)i5  * NW];                         \
        P##6  = mt2[(size_t)i6  * NW];                         \
        P##7  = mt2[(size_t)i7  * NW];                         \
        P##8  = mt2[(size_t)i8  * NW];                         \
        P##9  = mt2[(size_t)i9  * NW];                         \
        P##10 = mt2[(size_t)i10 * NW];                         \
        P##11 = mt2[(size_t)i11 * NW];                         \
        P##12 = mt2[(size_t)i12 * NW];                         \
        P##13 = mt2[(size_t)i13 * NW];                         \
        P##14 = mt2[(size_t)i14 * NW];                         \
        P##15 = mt2[(size_t)i15 * NW];                         \
        while (km) {  /* rare: kc > 16, fold immediately */    \
            int j = __ffsll(km) - 1; km &= km - 1;             \
            removed_t |= mt2[(size_t)j * NW];                  \
        }                                                      \
    }

#define FOLD(P)                                                           \
    removed_t |= ((P##0|P##1)|(P##2|P##3)) | ((P##4|P##5)|(P##6|P##7));   \
    removed_t |= ((P##8|P##9)|(P##10|P##11)) | ((P##12|P##13)|(P##14|P##15));

__global__ __launch_bounds__(256) void k_reduce(const float4* __restrict__ sboxes,
                                                const unsigned* __restrict__ ctrl,
                                                const u64* __restrict__ mask,
                                                const u64* __restrict__ dgsd,
                                                float4* __restrict__ out) {
    int tid = threadIdx.x;
    int lane = tid & 63;
    int wave = tid >> 6;
    unsigned cnt = ctrl[3];
    int C = (int)(cnt < (unsigned)CAP ? cnt : (unsigned)CAP);
    int nv = C < TOPK ? C : TOPK;
    int nblocks = (nv + 63) >> 6;

    __shared__ u64 s_rw[2];
    __shared__ u64 s_sup[4];                       // 4-slot rotation: read b&3,
    if (tid < 4) s_sup[tid] = 0ull;                //   OR into (b+1)&3, zero (b+2)&3

    u64 removed_t = ~0ull;                         // thread t owns column word t
    if (tid < NW) {
        long long lo = (long long)tid * 64;
        if (lo + 64 <= (long long)nv) removed_t = 0ull;
        else if (lo < (long long)nv)
            removed_t = ~((1ull << (unsigned)(nv - lo)) - 1ull);
    }

    u64 pA0=0,pA1=0,pA2=0,pA3=0,pA4=0,pA5=0,pA6=0,pA7=0;
    u64 pA8=0,pA9=0,pA10=0,pA11=0,pA12=0,pA13=0,pA14=0,pA15=0;
    u64 pB0=0,pB1=0,pB2=0,pB3=0,pB4=0,pB5=0,pB6=0,pB7=0;
    u64 pB8=0,pB9=0,pB10=0,pB11=0,pB12=0,pB13=0,pB14=0,pB15=0;

    const ulonglong2* D = (const ulonglong2*)dgsd;
    ulonglong2 dsnext = make_ulonglong2(0ull, 0ull);
    if (nblocks > 0) dsnext = D[lane];             // block 0 diag+superdiag

    int nk = 0;
    for (int b = 0; b < nblocks; ++b) {
        if ((b & 1) == 0) { FOLD(pA); } else { FOLD(pB); }   // loads from iter b-2
        ulonglong2 ds = dsnext;
        if (tid == b) s_rw[b & 1] = removed_t;     // word b: folds through b-2
        __syncthreads();
        u64 rw = s_rw[b & 1] | s_sup[b & 3];       // + block b-1's superdiag sup
        if (tid == 254) s_sup[(b + 2) & 3] = 0ull; // prep slot (barrier-separated)
        u64 dg = ds.x, sg = ds.y;
        if (b + 1 < nblocks) dsnext = D[(b + 1) * 64 + lane];

        // resolve via IoU symmetry: lane tests bits of ITS OWN diag word
        bool alive = ((rw >> lane) & 1ull) == 0ull;
        int budget = OUTN - nk;
        u64 keptmask = 0ull;
        int kc = 0;
        while (kc < budget) {
            u64 m = __ballot(alive);
            if (!m) break;
            int j = __ffsll(m) - 1;                // uniform
            keptmask |= (1ull << j);
            ++kc;
            alive = alive && (lane != j) && (((dg >> j) & 1ull) == 0ull);
        }

        if (wave == 0 && ((keptmask >> lane) & 1ull)) {
            int pos = nk + (int)__popcll(keptmask & ((1ull << lane) - 1ull));
            out[pos] = sboxes[b * 64 + lane];
            atomicOr(&s_sup[(b + 1) & 3], sg);     // sup for word b+1
        }
        nk += kc;
        if (nk >= OUTN) break;

        EXTRACT16();
        if ((b & 1) == 0) { ISSUE(pA); } else { ISSUE(pB); }
    }

    float4 z = make_float4(0.f, 0.f, 0.f, 0.f);
    for (int p = nk + tid; p < OUTN; p += 256) out[p] = z;
}

extern "C" void kernel_launch(void* const* d_in, const int* in_sizes, int n_in,
                              void* d_out, int out_size, void* d_ws, size_t ws_size,
                              hipStream_t stream) {
    const float4* delta = (const float4*)d_in[0];
    const float2* score = (const float2*)d_in[1];
    char* ws = (char*)d_ws;

    // Workspace layout (bytes)
    unsigned* ukey = (unsigned*)(ws + 0);          // N_ANCH u32
    u64*      cand = (u64*)(ws + 2359296);         // CAP u64
    unsigned* hist = (unsigned*)(ws + 2621440);    // 8192 u32 -- memset start
    unsigned* ctrl = (unsigned*)(ws + 2654208);    // 16 u32
    float4*   sbox = (float4*)(ws + 2654272);      // KPAD float4
    u64*      dgsd = (u64*)(ws + 2846784);         // 2*KPAD u64 {diag, superdiag}
    u64*      mask = (u64*)(ws + 3039296);         // KPAD*NW u64, ROW-major

    hipMemsetAsync(ws + 2621440, 0, 32832, stream);    // hist + ctrl

    k_score  <<<1024, 256, 0, stream>>>(delta, score, ukey, hist);
    k_compact<<<1024, 256, 0, stream>>>(ukey, hist, ctrl + 3, cand);
    k_rankdec<<<CAP/256, 256, 0, stream>>>(cand, ctrl, delta, sbox);
    dim3 mgrid(47, NW);
    k_mask   <<<mgrid, 64, 0, stream>>>(sbox, mask, dgsd);
    k_reduce <<<1,    256, 0, stream>>>(sbox, ctrl, mask, dgsd, (float4*)d_out);
}

// Round 13
// 1169.225 us; speedup vs baseline: 1.1590x; 1.0129x over previous
//
#include <hip/hip_runtime.h>

// Problem constants
#define N_ANCH   589824     // 256*256*9
#define TOPK     12000
#define KPAD     12032      // 188*64
#define NW       188        // mask words per row
#define OUTN     2000
#define CAP      32768      // candidate buffer capacity
#define NBIN     8192       // histogram bins (bits 31:19 of ordered key)

typedef unsigned long long u64;

// 9 base anchors (ratio-major, scale-minor), widths/heights (x1-x0+1)
__constant__ float c_aw[9] = {184.f, 368.f, 736.f, 128.f, 256.f, 512.f,  88.f, 176.f, 352.f};
__constant__ float c_ah[9] = { 96.f, 192.f, 384.f, 128.f, 256.f, 512.f, 176.f, 352.f, 704.f};

__device__ __forceinline__ void decode_one(int i, const float4* __restrict__ delta,
                                           float4* box, bool* valid) {
#pragma clang fp contract(off)
    int a    = i % 9;
    int cell = i / 9;
    int gx = cell & 255;
    int gy = cell >> 8;
    float w = c_aw[a], h = c_ah[a];
    float cx = (float)gx * 16.0f + 8.0f;
    float cy = (float)gy * 16.0f + 8.0f;
    float4 d = delta[i];
    float pcx = d.x * w + cx;
    float pcy = d.y * h + cy;
    float pw  = expf(d.z) * w;
    float ph  = expf(d.w) * h;
    float x0 = fminf(fmaxf(pcx - 0.5f * pw, 0.f), 4096.f);
    float y0 = fminf(fmaxf(pcy - 0.5f * ph, 0.f), 4096.f);
    float x1 = fminf(fmaxf(pcx + 0.5f * pw, 0.f), 4096.f);
    float y1 = fminf(fmaxf(pcy + 0.5f * ph, 0.f), 4096.f);
    *box = make_float4(x0, y0, x1, y1);
    *valid = (x1 - x0 >= 16.f) && (y1 - y0 >= 16.f);
}

// Decode + key + single 8192-bin LDS histogram (bits 31:19).
__global__ __launch_bounds__(256) void k_score(const float4* __restrict__ delta,
                                               const float2* __restrict__ score,
                                               unsigned* __restrict__ ukey,
                                               unsigned* __restrict__ hist) {
    __shared__ unsigned lh[NBIN];
    int tid = threadIdx.x;
    for (int k = tid; k < NBIN; k += 256) lh[k] = 0u;
    __syncthreads();
    for (int i = blockIdx.x * 256 + tid; i < N_ANCH; i += gridDim.x * 256) {
        float4 box; bool valid;
        decode_one(i, delta, &box, &valid);
        unsigned u = 0u;
        if (valid) {
            unsigned b = __float_as_uint(score[i].y);
            u = (b & 0x80000000u) ? ~b : (b | 0x80000000u);  // order-preserving; 0 = dead
        }
        ukey[i] = u;
        atomicAdd(&lh[u >> 19], 1u);
    }
    __syncthreads();
    for (int k = tid; k < NBIN; k += 256) {
        unsigned c = lh[k];
        if (c) atomicAdd(&hist[k], c);
    }
}

// Per-block redundant threshold scan (bin-exact) + compact.
__global__ __launch_bounds__(256) void k_compact(const unsigned* __restrict__ ukey,
                                                 const unsigned* __restrict__ hist,
                                                 unsigned* __restrict__ cnt,
                                                 u64* __restrict__ cand) {
    __shared__ unsigned ss[256];
    __shared__ unsigned s_B;
    int tid = threadIdx.x;
    int lane = tid & 63;
    const uint4* hb = (const uint4*)hist + tid * 8;    // 32 bins/thread
    unsigned cs = 0;
    #pragma unroll
    for (int k = 0; k < 8; ++k) {
        uint4 h = hb[k];
        cs += h.x + h.y + h.z + h.w;
    }
    ss[tid] = cs;
    if (tid == 0) s_B = 0u;
    __syncthreads();
    for (int d = 1; d < 256; d <<= 1) {                // suffix scan over chunk sums
        unsigned v = (tid + d < 256) ? ss[tid + d] : 0u;
        __syncthreads();
        ss[tid] += v;
        __syncthreads();
    }
    if (ss[tid] >= (unsigned)TOPK && (tid == 255 || ss[tid + 1] < (unsigned)TOPK)) {
        unsigned acc = (tid == 255) ? 0u : ss[tid + 1];
        unsigned B = (unsigned)(tid * 32);
        for (int j = 31; j >= 0; --j) {
            acc += hist[tid * 32 + j];
            if (acc >= (unsigned)TOPK) { B = (unsigned)(tid * 32 + j); break; }
        }
        s_B = B;
    }
    __syncthreads();
    unsigned B = s_B;
    for (int i = blockIdx.x * 256 + tid; i < N_ANCH; i += gridDim.x * 256) {
        unsigned u = ukey[i];
        bool pred = (u != 0u) && ((u >> 19) >= B);
        u64 m = __ballot(pred);
        if (m) {
            int leader = __ffsll(m) - 1;
            unsigned base = 0;
            if (lane == leader) base = atomicAdd(cnt, (unsigned)__popcll(m));
            base = __shfl(base, leader);
            if (pred) {
                u64 below = m & ((1ull << lane) - 1ull);
                unsigned pos = base + (unsigned)__popcll(below);
                if (pos < CAP) cand[pos] = ((u64)u << 32) | (unsigned)(~i);
            }
        }
    }
}

// Exact rank + decode into sbox; zero-fills pad ranks [nv, KPAD) (disjoint, race-free).
__global__ __launch_bounds__(256) void k_rankdec(const u64* __restrict__ cand,
                                                 const unsigned* __restrict__ ctrl,
                                                 const float4* __restrict__ delta,
                                                 float4* __restrict__ sboxes) {
    unsigned cnt = ctrl[3];
    int C = (int)(cnt < (unsigned)CAP ? cnt : (unsigned)CAP);
    int nv = C < TOPK ? C : TOPK;
    int t = blockIdx.x * 256 + threadIdx.x;
    if (t >= nv && t < KPAD) sboxes[t] = make_float4(0.f, 0.f, 0.f, 0.f);
    if ((int)(blockIdx.x * 256) >= C) return;
    u64 mykey = (t < C) ? cand[t] : ~0ull;
    int rank = 0;
    __shared__ u64 tile[256];
    for (int j0 = 0; j0 < C; j0 += 256) {
        int j = j0 + threadIdx.x;
        tile[threadIdx.x] = (j < C) ? cand[j] : 0ull;
        __syncthreads();
        int lim = (C - j0 < 256) ? (C - j0) : 256;
        #pragma unroll 4
        for (int jj = 0; jj < lim; ++jj) rank += (tile[jj] > mykey) ? 1 : 0;
        __syncthreads();
    }
    if (t < C && rank < TOPK) {
        int idx = (int)(~(unsigned)mykey);
        float4 box; bool v;
        decode_one(idx, delta, &box, &v);
        sboxes[rank] = box;
    }
}

// Suppression bitmask, ROW-major mask[r*NW+cb], upper triangle. Also writes
// dgsd[r] = {diag word, superdiag word} for the reduce's coalesced prefetch.
__global__ __launch_bounds__(64) void k_mask(const float4* __restrict__ sboxes,
                                             u64* __restrict__ mask,
                                             u64* __restrict__ dgsd) {
    int rb = blockIdx.y;
    int cb0 = blockIdx.x * 4;
    if (cb0 + 3 < rb) return;
    int tid = threadIdx.x;
    int r = rb * 64 + tid;
    float4 me = sboxes[r];
    float areaMe = (me.z - me.x) * (me.w - me.y);
    if (rb == NW - 1 && cb0 == (NW - 1) / 4 * 4)
        dgsd[2 * r + 1] = 0ull;                   // last block has no superdiag
    __shared__ float4 cbox[64];
    for (int q = 0; q < 4; ++q) {                 // wave-uniform guard: 1-wave block
        int cb = cb0 + q;
        if (cb < rb) continue;
        __syncthreads();
        cbox[tid] = sboxes[cb * 64 + tid];
        __syncthreads();
        u64 bits = 0ull;
        for (int j = 0; j < 64; ++j) {
            float4 o = cbox[j];
            float xx0 = fmaxf(me.x, o.x);
            float yy0 = fmaxf(me.y, o.y);
            float xx1 = fminf(me.z, o.z);
            float yy1 = fminf(me.w, o.w);
            float iw = fmaxf(xx1 - xx0, 0.f);
            float ih = fmaxf(yy1 - yy0, 0.f);
            float inter = iw * ih;
            float areaO = (o.z - o.x) * (o.w - o.y);
            float denom = fmaxf(areaMe + areaO - inter, 1e-8f);
            float iou = inter / denom;
            if (iou > 0.7f && (cb * 64 + j) != r) bits |= (1ull << j);
        }
        mask[(size_t)r * NW + cb] = bits;
        if (cb == rb)     dgsd[2 * r]     = bits;   // diagonal word
        if (cb == rb + 1) dgsd[2 * r + 1] = bits;   // superdiagonal word
    }
}

// Blocked greedy reduce, publish-early / fold-mid, 16 pending regs (lag-1):
// - word b publish = removed_t (strips through block b-2) | s_sup (block b-1's
//   superdiag, OR'd in-register from dgsd -- no memory dependency).
// - strip loads issued at end of iter b-1 fold AFTER iter b's resolve:
//   latency window = publish + barrier + resolve (~600cyc), single pending set.
// - kept boxes recorded in LDS; output expansion is a parallel epilogue.
__global__ __launch_bounds__(256) void k_reduce(const float4* __restrict__ sboxes,
                                                const unsigned* __restrict__ ctrl,
                                                const u64* __restrict__ mask,
                                                const u64* __restrict__ dgsd,
                                                float4* __restrict__ out) {
    int tid = threadIdx.x;
    int lane = tid & 63;
    int wave = tid >> 6;
    unsigned cnt = ctrl[3];
    int C = (int)(cnt < (unsigned)CAP ? cnt : (unsigned)CAP);
    int nv = C < TOPK ? C : TOPK;
    int nblocks = (nv + 63) >> 6;

    __shared__ u64 s_rw[2];
    __shared__ u64 s_sup[4];        // rotation: read b&3, OR (b+1)&3, zero (b+2)&3
    __shared__ u64 s_kept[NW];
    __shared__ unsigned s_nkb[NW];
    if (tid < 4) s_sup[tid] = 0ull;

    u64 removed_t = ~0ull;                         // thread t owns column word t
    if (tid < NW) {
        long long lo = (long long)tid * 64;
        if (lo + 64 <= (long long)nv) removed_t = 0ull;
        else if (lo < (long long)nv)
            removed_t = ~((1ull << (unsigned)(nv - lo)) - 1ull);
    }

    u64 p0=0,p1=0,p2=0,p3=0,p4=0,p5=0,p6=0,p7=0;
    u64 p8=0,p9=0,p10=0,p11=0,p12=0,p13=0,p14=0,p15=0;

    const ulonglong2* D = (const ulonglong2*)dgsd;
    ulonglong2 dsnext = make_ulonglong2(0ull, 0ull);
    if (nblocks > 0) dsnext = D[lane];             // block 0 {diag, superdiag}

    int nk = 0;
    int blim = nblocks;
    for (int b = 0; b < nblocks; ++b) {
        ulonglong2 ds = dsnext;
        if (tid == b) s_rw[b & 1] = removed_t;     // strips through block b-2
        __syncthreads();                           // one barrier per iteration
        u64 rw = s_rw[b & 1] | s_sup[b & 3];       // + block b-1's superdiag
        if (tid == 254) s_sup[(b + 2) & 3] = 0ull;
        u64 dg = ds.x, sg = ds.y;
        if (b + 1 < nblocks) dsnext = D[(b + 1) * 64 + lane];

        // resolve via IoU symmetry: lane tests bits of ITS OWN diag word
        bool alive = ((rw >> lane) & 1ull) == 0ull;
        int budget = OUTN - nk;
        u64 keptmask = 0ull;
        int kc = 0;
        while (kc < budget) {
            u64 m = __ballot(alive);
            if (!m) break;
            int j = __ffsll(m) - 1;                // uniform
            keptmask |= (1ull << j);
            ++kc;
            alive = alive && (lane != j) && (((dg >> j) & 1ull) == 0ull);
        }

        // fold strips issued last iteration (window: publish+barrier+resolve)
        removed_t |= ((p0|p1)|(p2|p3)) | ((p4|p5)|(p6|p7));
        removed_t |= ((p8|p9)|(p10|p11)) | ((p12|p13)|(p14|p15));
        p0=p1=p2=p3=p4=p5=p6=p7=0ull;
        p8=p9=p10=p11=p12=p13=p14=p15=0ull;

        if (tid == 0) { s_kept[b] = keptmask; s_nkb[b] = (unsigned)nk; }
        if (wave == 0 && ((keptmask >> lane) & 1ull))
            atomicOr(&s_sup[(b + 1) & 3], sg);     // superdiag sup for word b+1

        nk += kc;
        if (nk >= OUTN) { blim = b + 1; break; }

        // issue strip loads for block b's kept rows (fold at iter b+1)
        u64 km = keptmask;
        int jf = __ffsll(km) - 1;
        int i0 = jf;                          km &= km - 1;
        int i1  = km ? __ffsll(km) - 1 : jf;  km &= km - 1;
        int i2  = km ? __ffsll(km) - 1 : jf;  km &= km - 1;
        int i3  = km ? __ffsll(km) - 1 : jf;  km &= km - 1;
        int i4  = km ? __ffsll(km) - 1 : jf;  km &= km - 1;
        int i5  = km ? __ffsll(km) - 1 : jf;  km &= km - 1;
        int i6  = km ? __ffsll(km) - 1 : jf;  km &= km - 1;
        int i7  = km ? __ffsll(km) - 1 : jf;  km &= km - 1;
        int i8  = km ? __ffsll(km) - 1 : jf;  km &= km - 1;
        int i9  = km ? __ffsll(km) - 1 : jf;  km &= km - 1;
        int i10 = km ? __ffsll(km) - 1 : jf;  km &= km - 1;
        int i11 = km ? __ffsll(km) - 1 : jf;  km &= km - 1;
        int i12 = km ? __ffsll(km) - 1 : jf;  km &= km - 1;
        int i13 = km ? __ffsll(km) - 1 : jf;  km &= km - 1;
        int i14 = km ? __ffsll(km) - 1 : jf;  km &= km - 1;
        int i15 = km ? __ffsll(km) - 1 : jf;  km &= km - 1;
        if (kc > 0 && tid > b + 1 && tid < NW) {
            const u64* mt2 = mask + (size_t)b * 64 * NW + tid;
            p0  = mt2[(size_t)i0  * NW];
            p1  = mt2[(size_t)i1  * NW];
            p2  = mt2[(size_t)i2  * NW];
            p3  = mt2[(size_t)i3  * NW];
            p4  = mt2[(size_t)i4  * NW];
            p5  = mt2[(size_t)i5  * NW];
            p6  = mt2[(size_t)i6  * NW];
            p7  = mt2[(size_t)i7  * NW];
            p8  = mt2[(size_t)i8  * NW];
            p9  = mt2[(size_t)i9  * NW];
            p10 = mt2[(size_t)i10 * NW];
            p11 = mt2[(size_t)i11 * NW];
            p12 = mt2[(size_t)i12 * NW];
            p13 = mt2[(size_t)i13 * NW];
            p14 = mt2[(size_t)i14 * NW];
            p15 = mt2[(size_t)i15 * NW];
            while (km) {                           // rare: kc > 16
                int j = __ffsll(km) - 1; km &= km - 1;
                removed_t |= mt2[(size_t)j * NW];
            }
        }
    }
    __syncthreads();

    // parallel output expansion: 4 blocks per pass, wave w handles block b4+w
    for (int b4 = 0; b4 < blim; b4 += 4) {
        int b = b4 + wave;
        if (b < blim) {
            u64 km = s_kept[b];
            if ((km >> lane) & 1ull) {
                int pos = (int)s_nkb[b] + (int)__popcll(km & ((1ull << lane) - 1ull));
                out[pos] = sboxes[b * 64 + lane];
            }
        }
    }
    float4 z = make_float4(0.f, 0.f, 0.f, 0.f);
    for (int p = nk + tid; p < OUTN; p += 256) out[p] = z;
}

extern "C" void kernel_launch(void* const* d_in, const int* in_sizes, int n_in,
                              void* d_out, int out_size, void* d_ws, size_t ws_size,
                              hipStream_t stream) {
    const float4* delta = (const float4*)d_in[0];
    const float2* score = (const float2*)d_in[1];
    char* ws = (char*)d_ws;

    // Workspace layout (bytes)
    unsigned* ukey = (unsigned*)(ws + 0);          // N_ANCH u32
    u64*      cand = (u64*)(ws + 2359296);         // CAP u64
    unsigned* hist = (unsigned*)(ws + 2621440);    // 8192 u32 -- memset start
    unsigned* ctrl = (unsigned*)(ws + 2654208);    // 16 u32
    float4*   sbox = (float4*)(ws + 2654272);      // KPAD float4
    u64*      dgsd = (u64*)(ws + 2846784);         // 2*KPAD u64 {diag, superdiag}
    u64*      mask = (u64*)(ws + 3039296);         // KPAD*NW u64, ROW-major

    hipMemsetAsync(ws + 2621440, 0, 32832, stream);    // hist + ctrl

    k_score  <<<1024, 256, 0, stream>>>(delta, score, ukey, hist);
    k_compact<<<1024, 256, 0, stream>>>(ukey, hist, ctrl + 3, cand);
    k_rankdec<<<CAP/256, 256, 0, stream>>>(cand, ctrl, delta, sbox);
    dim3 mgrid(47, NW);
    k_mask   <<<mgrid, 64, 0, stream>>>(sbox, mask, dgsd);
    k_reduce <<<1,    256, 0, stream>>>(sbox, ctrl, mask, dgsd, (float4*)d_out);
}

// Round 14
// 1149.092 us; speedup vs baseline: 1.1793x; 1.0175x over previous
//
#include <hip/hip_runtime.h>

// Problem constants
#define N_ANCH   589824     // 256*256*9
#define TOPK     12000
#define KPAD     12032      // 188*64
#define NW       188        // mask words per row
#define OUTN     2000
#define CAP      32768      // candidate buffer capacity
#define NBIN     8192       // histogram bins (bits 31:19 of ordered key)

typedef unsigned long long u64;

// 9 base anchors (ratio-major, scale-minor), widths/heights (x1-x0+1)
__constant__ float c_aw[9] = {184.f, 368.f, 736.f, 128.f, 256.f, 512.f,  88.f, 176.f, 352.f};
__constant__ float c_ah[9] = { 96.f, 192.f, 384.f, 128.f, 256.f, 512.f, 176.f, 352.f, 704.f};

__device__ __forceinline__ void decode_one(int i, const float4* __restrict__ delta,
                                           float4* box, bool* valid) {
#pragma clang fp contract(off)
    int a    = i % 9;
    int cell = i / 9;
    int gx = cell & 255;
    int gy = cell >> 8;
    float w = c_aw[a], h = c_ah[a];
    float cx = (float)gx * 16.0f + 8.0f;
    float cy = (float)gy * 16.0f + 8.0f;
    float4 d = delta[i];
    float pcx = d.x * w + cx;
    float pcy = d.y * h + cy;
    float pw  = expf(d.z) * w;
    float ph  = expf(d.w) * h;
    float x0 = fminf(fmaxf(pcx - 0.5f * pw, 0.f), 4096.f);
    float y0 = fminf(fmaxf(pcy - 0.5f * ph, 0.f), 4096.f);
    float x1 = fminf(fmaxf(pcx + 0.5f * pw, 0.f), 4096.f);
    float y1 = fminf(fmaxf(pcy + 0.5f * ph, 0.f), 4096.f);
    *box = make_float4(x0, y0, x1, y1);
    *valid = (x1 - x0 >= 16.f) && (y1 - y0 >= 16.f);
}

// Decode + key + single 8192-bin LDS histogram (bits 31:19).
__global__ __launch_bounds__(256) void k_score(const float4* __restrict__ delta,
                                               const float2* __restrict__ score,
                                               unsigned* __restrict__ ukey,
                                               unsigned* __restrict__ hist) {
    __shared__ unsigned lh[NBIN];
    int tid = threadIdx.x;
    for (int k = tid; k < NBIN; k += 256) lh[k] = 0u;
    __syncthreads();
    for (int i = blockIdx.x * 256 + tid; i < N_ANCH; i += gridDim.x * 256) {
        float4 box; bool valid;
        decode_one(i, delta, &box, &valid);
        unsigned u = 0u;
        if (valid) {
            unsigned b = __float_as_uint(score[i].y);
            u = (b & 0x80000000u) ? ~b : (b | 0x80000000u);  // order-preserving; 0 = dead
        }
        ukey[i] = u;
        atomicAdd(&lh[u >> 19], 1u);
    }
    __syncthreads();
    for (int k = tid; k < NBIN; k += 256) {
        unsigned c = lh[k];
        if (c) atomicAdd(&hist[k], c);
    }
}

// Per-block redundant threshold scan (bin-exact) + compact.
__global__ __launch_bounds__(256) void k_compact(const unsigned* __restrict__ ukey,
                                                 const unsigned* __restrict__ hist,
                                                 unsigned* __restrict__ cnt,
                                                 u64* __restrict__ cand) {
    __shared__ unsigned ss[256];
    __shared__ unsigned s_B;
    int tid = threadIdx.x;
    int lane = tid & 63;
    const uint4* hb = (const uint4*)hist + tid * 8;    // 32 bins/thread
    unsigned cs = 0;
    #pragma unroll
    for (int k = 0; k < 8; ++k) {
        uint4 h = hb[k];
        cs += h.x + h.y + h.z + h.w;
    }
    ss[tid] = cs;
    if (tid == 0) s_B = 0u;
    __syncthreads();
    for (int d = 1; d < 256; d <<= 1) {                // suffix scan over chunk sums
        unsigned v = (tid + d < 256) ? ss[tid + d] : 0u;
        __syncthreads();
        ss[tid] += v;
        __syncthreads();
    }
    if (ss[tid] >= (unsigned)TOPK && (tid == 255 || ss[tid + 1] < (unsigned)TOPK)) {
        unsigned acc = (tid == 255) ? 0u : ss[tid + 1];
        unsigned B = (unsigned)(tid * 32);
        for (int j = 31; j >= 0; --j) {
            acc += hist[tid * 32 + j];
            if (acc >= (unsigned)TOPK) { B = (unsigned)(tid * 32 + j); break; }
        }
        s_B = B;
    }
    __syncthreads();
    unsigned B = s_B;
    for (int i = blockIdx.x * 256 + tid; i < N_ANCH; i += gridDim.x * 256) {
        unsigned u = ukey[i];
        bool pred = (u != 0u) && ((u >> 19) >= B);
        u64 m = __ballot(pred);
        if (m) {
            int leader = __ffsll(m) - 1;
            unsigned base = 0;
            if (lane == leader) base = atomicAdd(cnt, (unsigned)__popcll(m));
            base = __shfl(base, leader);
            if (pred) {
                u64 below = m & ((1ull << lane) - 1ull);
                unsigned pos = base + (unsigned)__popcll(below);
                if (pos < CAP) cand[pos] = ((u64)u << 32) | (unsigned)(~i);
            }
        }
    }
}

// Exact rank + decode into sbox; zero-fills pad ranks [nv, KPAD) (disjoint, race-free).
__global__ __launch_bounds__(256) void k_rankdec(const u64* __restrict__ cand,
                                                 const unsigned* __restrict__ ctrl,
                                                 const float4* __restrict__ delta,
                                                 float4* __restrict__ sboxes) {
    unsigned cnt = ctrl[3];
    int C = (int)(cnt < (unsigned)CAP ? cnt : (unsigned)CAP);
    int nv = C < TOPK ? C : TOPK;
    int t = blockIdx.x * 256 + threadIdx.x;
    if (t >= nv && t < KPAD) sboxes[t] = make_float4(0.f, 0.f, 0.f, 0.f);
    if ((int)(blockIdx.x * 256) >= C) return;
    u64 mykey = (t < C) ? cand[t] : ~0ull;
    int rank = 0;
    __shared__ u64 tile[256];
    for (int j0 = 0; j0 < C; j0 += 256) {
        int j = j0 + threadIdx.x;
        tile[threadIdx.x] = (j < C) ? cand[j] : 0ull;
        __syncthreads();
        int lim = (C - j0 < 256) ? (C - j0) : 256;
        #pragma unroll 4
        for (int jj = 0; jj < lim; ++jj) rank += (tile[jj] > mykey) ? 1 : 0;
        __syncthreads();
    }
    if (t < C && rank < TOPK) {
        int idx = (int)(~(unsigned)mykey);
        float4 box; bool v;
        decode_one(idx, delta, &box, &v);
        sboxes[rank] = box;
    }
}

// Suppression bitmask, ROW-major mask[r*NW+cb], upper triangle. Also writes
// dgsd[r] = {diag word, superdiag word} for the reduce's coalesced prefetch.
__global__ __launch_bounds__(64) void k_mask(const float4* __restrict__ sboxes,
                                             u64* __restrict__ mask,
                                             u64* __restrict__ dgsd) {
    int rb = blockIdx.y;
    int cb0 = blockIdx.x * 4;
    if (cb0 + 3 < rb) return;
    int tid = threadIdx.x;
    int r = rb * 64 + tid;
    float4 me = sboxes[r];
    float areaMe = (me.z - me.x) * (me.w - me.y);
    if (rb == NW - 1 && cb0 == (NW - 1) / 4 * 4)
        dgsd[2 * r + 1] = 0ull;                   // last block has no superdiag
    __shared__ float4 cbox[64];
    for (int q = 0; q < 4; ++q) {                 // wave-uniform guard: 1-wave block
        int cb = cb0 + q;
        if (cb < rb) continue;
        __syncthreads();
        cbox[tid] = sboxes[cb * 64 + tid];
        __syncthreads();
        u64 bits = 0ull;
        for (int j = 0; j < 64; ++j) {
            float4 o = cbox[j];
            float xx0 = fmaxf(me.x, o.x);
            float yy0 = fmaxf(me.y, o.y);
            float xx1 = fminf(me.z, o.z);
            float yy1 = fminf(me.w, o.w);
            float iw = fmaxf(xx1 - xx0, 0.f);
            float ih = fmaxf(yy1 - yy0, 0.f);
            float inter = iw * ih;
            float areaO = (o.z - o.x) * (o.w - o.y);
            float denom = fmaxf(areaMe + areaO - inter, 1e-8f);
            float iou = inter / denom;
            if (iou > 0.7f && (cb * 64 + j) != r) bits |= (1ull << j);
        }
        mask[(size_t)r * NW + cb] = bits;
        if (cb == rb)     dgsd[2 * r]     = bits;   // diagonal word
        if (cb == rb + 1) dgsd[2 * r + 1] = bits;   // superdiagonal word
    }
}

// wave-wide OR reduce of a u64 (two 32-bit shfl_xor per step, 6 steps)
__device__ __forceinline__ u64 wave_or64(u64 v) {
    #pragma unroll
    for (int d = 1; d < 64; d <<= 1) {
        unsigned lo = (unsigned)v;
        unsigned hi = (unsigned)(v >> 32);
        lo |= __shfl_xor(lo, d);
        hi |= __shfl_xor(hi, d);
        v = ((u64)hi << 32) | lo;
    }
    return v;
}

// ballot resolve: greedy within one 64-block given starting removed word rw and
// diag word dg (lane's own row). Uniform result in every wave.
__device__ __forceinline__ u64 resolve64(u64 rw, u64 dg, int lane, int budget, int* kc_out) {
    bool alive = ((rw >> lane) & 1ull) == 0ull;
    u64 keptmask = 0ull;
    int kc = 0;
    while (kc < budget) {
        u64 m = __ballot(alive);
        if (!m) break;
        int j = __ffsll(m) - 1;                // uniform
        keptmask |= (1ull << j);
        ++kc;
        alive = alive && (lane != j) && (((dg >> j) & 1ull) == 0ull);
    }
    *kc_out = kc;
    return keptmask;
}

// extract up to 12 set-bit indices (padded with first index; remainder in km)
#define EXTRACT12(KM, I)                                        \
    int I##f = __ffsll(KM) - 1;                                 \
    int I##0 = I##f;                          KM &= KM - 1;     \
    int I##1  = KM ? __ffsll(KM) - 1 : I##f;  KM &= KM - 1;     \
    int I##2  = KM ? __ffsll(KM) - 1 : I##f;  KM &= KM - 1;     \
    int I##3  = KM ? __ffsll(KM) - 1 : I##f;  KM &= KM - 1;     \
    int I##4  = KM ? __ffsll(KM) - 1 : I##f;  KM &= KM - 1;     \
    int I##5  = KM ? __ffsll(KM) - 1 : I##f;  KM &= KM - 1;     \
    int I##6  = KM ? __ffsll(KM) - 1 : I##f;  KM &= KM - 1;     \
    int I##7  = KM ? __ffsll(KM) - 1 : I##f;  KM &= KM - 1;     \
    int I##8  = KM ? __ffsll(KM) - 1 : I##f;  KM &= KM - 1;     \
    int I##9  = KM ? __ffsll(KM) - 1 : I##f;  KM &= KM - 1;     \
    int I##10 = KM ? __ffsll(KM) - 1 : I##f;  KM &= KM - 1;     \
    int I##11 = KM ? __ffsll(KM) - 1 : I##f;  KM &= KM - 1;

// Blocked greedy reduce, TWO 64-rank blocks per iteration (94 iters):
// - removed bitmap rem[NW] in LDS (thread t owns word t; plain writes).
// - intra-pair dependency via superdiag words: sup = wave-OR of dgsd[r].y over
//   block b's kept lanes (in-register shfl tree, no memory).
// - strips for both blocks fold IMMEDIATELY (R4's winning trait), one vmem
//   stall + one barrier per pair.
__global__ __launch_bounds__(256) void k_reduce(const float4* __restrict__ sboxes,
                                                const unsigned* __restrict__ ctrl,
                                                const u64* __restrict__ mask,
                                                const u64* __restrict__ dgsd,
                                                float4* __restrict__ out) {
    int tid = threadIdx.x;
    int lane = tid & 63;
    int wave = tid >> 6;
    unsigned cnt = ctrl[3];
    int C = (int)(cnt < (unsigned)CAP ? cnt : (unsigned)CAP);
    int nv = C < TOPK ? C : TOPK;
    int nblocks = (nv + 63) >> 6;

    __shared__ u64 rem[NW];
    __shared__ u64 s_kept[NW];
    __shared__ unsigned s_nkb[NW];

    if (tid < NW) {                                // thread t owns rem[t]
        long long lo = (long long)tid * 64;
        u64 r0 = ~0ull;
        if (lo + 64 <= (long long)nv) r0 = 0ull;
        else if (lo < (long long)nv)
            r0 = ~((1ull << (unsigned)(nv - lo)) - 1ull);
        rem[tid] = r0;
    }

    const ulonglong2* D = (const ulonglong2*)dgsd;
    ulonglong2 zero2 = make_ulonglong2(0ull, 0ull);
    ulonglong2 dAn = zero2, dBn = zero2;
    if (nblocks > 0) dAn = D[lane];
    if (nblocks > 1) dBn = D[64 + lane];

    int nk = 0;
    int blim = nblocks;
    for (int b = 0; b < nblocks; b += 2) {
        bool hasB = (b + 1 < nblocks);
        ulonglong2 dA = dAn, dB = dBn;
        __syncthreads();                           // rem[] current through b-1
        u64 rw0 = rem[b];
        u64 rw1 = hasB ? rem[b + 1] : ~0ull;
        if (b + 2 < nblocks) {                     // prefetch next pair
            dAn = D[(b + 2) * 64 + lane];
            dBn = (b + 3 < nblocks) ? D[(b + 3) * 64 + lane] : zero2;
        }

        // resolve block b
        int kc0;
        u64 kept0 = resolve64(rw0, dA.x, lane, OUTN - nk, &kc0);
        // superdiag sup: OR of dA.y over kept lanes (in-register tree)
        u64 sup = wave_or64(((kept0 >> lane) & 1ull) ? dA.y : 0ull);
        // resolve block b+1
        int kc1 = 0;
        u64 kept1 = 0ull;
        if (hasB) kept1 = resolve64(rw1 | sup, dB.x, lane, OUTN - nk - kc0, &kc1);

        if (tid == 0) {
            s_kept[b] = kept0; s_nkb[b] = (unsigned)nk;
            if (hasB) { s_kept[b + 1] = kept1; s_nkb[b + 1] = (unsigned)(nk + kc0); }
        }
        nk += kc0 + kc1;
        if (nk >= OUTN) { blim = hasB ? b + 2 : b + 1; break; }

        // strip loads + IMMEDIATE fold into rem[tid] (columns t >= b+2 only)
        if ((kc0 + kc1) > 0 && tid > b + 1 && tid < NW) {
            u64 acc = 0ull;
            const u64* m0 = mask + (size_t)b * 64 * NW + tid;
            const u64* m1 = mask + (size_t)(b + 1) * 64 * NW + tid;
            if (kc0 > 0) {
                u64 km = kept0;
                EXTRACT12(km, a);
                u64 v0 = m0[(size_t)a0 * NW],  v1 = m0[(size_t)a1 * NW];
                u64 v2 = m0[(size_t)a2 * NW],  v3 = m0[(size_t)a3 * NW];
                u64 v4 = m0[(size_t)a4 * NW],  v5 = m0[(size_t)a5 * NW];
                u64 v6 = m0[(size_t)a6 * NW],  v7 = m0[(size_t)a7 * NW];
                u64 v8 = m0[(size_t)a8 * NW],  v9 = m0[(size_t)a9 * NW];
                u64 v10 = m0[(size_t)a10 * NW], v11 = m0[(size_t)a11 * NW];
                acc |= ((v0|v1)|(v2|v3)) | ((v4|v5)|(v6|v7)) | ((v8|v9)|(v10|v11));
                while (km) { int j = __ffsll(km) - 1; km &= km - 1;
                             acc |= m0[(size_t)j * NW]; }
            }
            if (kc1 > 0) {
                u64 km = kept1;
                EXTRACT12(km, c);
                u64 w0 = m1[(size_t)c0 * NW],  w1 = m1[(size_t)c1 * NW];
                u64 w2 = m1[(size_t)c2 * NW],  w3 = m1[(size_t)c3 * NW];
                u64 w4 = m1[(size_t)c4 * NW],  w5 = m1[(size_t)c5 * NW];
                u64 w6 = m1[(size_t)c6 * NW],  w7 = m1[(size_t)c7 * NW];
                u64 w8 = m1[(size_t)c8 * NW],  w9 = m1[(size_t)c9 * NW];
                u64 w10 = m1[(size_t)c10 * NW], w11 = m1[(size_t)c11 * NW];
                acc |= ((w0|w1)|(w2|w3)) | ((w4|w5)|(w6|w7)) | ((w8|w9)|(w10|w11));
                while (km) { int j = __ffsll(km) - 1; km &= km - 1;
                             acc |= m1[(size_t)j * NW]; }
            }
            rem[tid] |= acc;                       // plain write, thread-owned
        }
        // next iteration's barrier orders rem[] for the pair b+2
    }
    __syncthreads();

    // parallel output expansion: 4 blocks per pass, wave w handles block b4+w
    for (int b4 = 0; b4 < blim; b4 += 4) {
        int b = b4 + wave;
        if (b < blim) {
            u64 km = s_kept[b];
            if ((km >> lane) & 1ull) {
                int pos = (int)s_nkb[b] + (int)__popcll(km & ((1ull << lane) - 1ull));
                out[pos] = sboxes[b * 64 + lane];
            }
        }
    }
    float4 z = make_float4(0.f, 0.f, 0.f, 0.f);
    for (int p = nk + tid; p < OUTN; p += 256) out[p] = z;
}

extern "C" void kernel_launch(void* const* d_in, const int* in_sizes, int n_in,
                              void* d_out, int out_size, void* d_ws, size_t ws_size,
                              hipStream_t stream) {
    const float4* delta = (const float4*)d_in[0];
    const float2* score = (const float2*)d_in[1];
    char* ws = (char*)d_ws;

    // Workspace layout (bytes)
    unsigned* ukey = (unsigned*)(ws + 0);          // N_ANCH u32
    u64*      cand = (u64*)(ws + 2359296);         // CAP u64
    unsigned* hist = (unsigned*)(ws + 2621440);    // 8192 u32 -- memset start
    unsigned* ctrl = (unsigned*)(ws + 2654208);    // 16 u32
    float4*   sbox = (float4*)(ws + 2654272);      // KPAD float4
    u64*      dgsd = (u64*)(ws + 2846784);         // 2*KPAD u64 {diag, superdiag}
    u64*      mask = (u64*)(ws + 3039296);         // KPAD*NW u64, ROW-major

    hipMemsetAsync(ws + 2621440, 0, 32832, stream);    // hist + ctrl

    k_score  <<<1024, 256, 0, stream>>>(delta, score, ukey, hist);
    k_compact<<<1024, 256, 0, stream>>>(ukey, hist, ctrl + 3, cand);
    k_rankdec<<<CAP/256, 256, 0, stream>>>(cand, ctrl, delta, sbox);
    dim3 mgrid(47, NW);
    k_mask   <<<mgrid, 64, 0, stream>>>(sbox, mask, dgsd);
    k_reduce <<<1,    256, 0, stream>>>(sbox, ctrl, mask, dgsd, (float4*)d_out);
}